// Round 13
// baseline (94.080 us; speedup 1.0000x reference)
//
#include <hip/hip_runtime.h>
#include <stdint.h>

#define KK 5
#define TT 512

// ---- cross-lane helpers (8-lane groups; 8 | 32 so groups never straddle the
// ds_swizzle 32-lane boundary) ----
template<int P> __device__ __forceinline__ float swzf(float v) {
  return __int_as_float(__builtin_amdgcn_ds_swizzle(__float_as_int(v), P));
}
template<int P> __device__ __forceinline__ int swzi(int v) {
  return __builtin_amdgcn_ds_swizzle(v, P);
}
// broadcast lane (group*8 + i): offset = (i<<5) | 0x18
#define BC0 0x018
#define BC1 0x038
#define BC2 0x058
#define BC3 0x078
#define BC4 0x098
// xor-butterfly within 8-lane group: offset = (m<<10) | 0x1F
#define X1 0x041F
#define X2 0x081F
#define X4 0x101F

__device__ __forceinline__ float sel5f(float v0,float v1,float v2,float v3,float v4,int ct){
  float u=v0; u=(ct==1)?v1:u; u=(ct==2)?v2:u; u=(ct==3)?v3:u; u=(ct==4)?v4:u; return u;
}
__device__ __forceinline__ uint32_t sel5u(uint32_t w0,uint32_t w1,uint32_t w2,uint32_t w3,uint32_t w4,int ct){
  uint32_t u=w0; u=(ct==1)?w1:u; u=(ct==2)?w2:u; u=(ct==3)?w3:u; u=(ct==4)?w4:u; return u;
}
__device__ __forceinline__ int telt(const int4 (&tp)[2], int s) {   // s compile-time
  const int4 v = (s < 4) ? tp[0] : tp[1];
  const int m = s & 3;
  return m == 0 ? v.x : (m == 1 ? v.y : (m == 2 ? v.z : v.w));
}

// load one 8-step column block: element t for t = 8k+1 .. 8k+8 (clamped)
__device__ __forceinline__ void loadCol(float (&d)[8], const float* __restrict__ colp, int k) {
  const int t0 = k * 8 + 1;
  if (k < TT / 8 - 1) {
#pragma unroll
    for (int s = 0; s < 8; ++s) d[s] = colp[(t0 + s) * KK];
  } else {
#pragma unroll
    for (int s = 0; s < 8; ++s) d[s] = colp[min(t0 + s, TT - 1) * KK];
  }
}
// aligned tag window [8k, 8k+7]
__device__ __forceinline__ void loadTag(int4 (&tp)[2], const int* __restrict__ tg, int k) {
  tp[0] = *(const int4*)(tg + 8 * k);
  tp[1] = *(const int4*)(tg + 8 * k + 4);
}

// ---------------------------------------------------------------------------
// Kernel 0: counting sort of batch indices by length (1 block, 1024 threads).
// Output permutation order[0..B): lengths ascending. Wave groups of 8 sorted-
// adjacent batches get nblk ~= their own length instead of max-of-8-random.
// ---------------------------------------------------------------------------
__global__ void sort_by_len(const int* __restrict__ lens, int* __restrict__ order, int B) {
  __shared__ int hist[513];
  __shared__ int off[513];
  const int tid = threadIdx.x;
  for (int i = tid; i < 513; i += 1024) hist[i] = 0;
  __syncthreads();
  for (int b = tid; b < B; b += 1024) atomicAdd(&hist[lens[b]], 1);
  __syncthreads();
  if (tid < 64) {
    int local[9];
    int sum = 0;
#pragma unroll
    for (int j = 0; j < 9; ++j) {
      const int i = tid * 9 + j;              // covers 0..575 >= 513
      const int v = (i < 513) ? hist[i] : 0;
      local[j] = sum;                          // lane-local exclusive
      sum += v;
    }
    int inc = sum;                             // wave inclusive scan
#pragma unroll
    for (int d = 1; d < 64; d <<= 1) {
      const int n = __shfl_up(inc, d);
      inc += (tid >= d) ? n : 0;
    }
    const int excl = inc - sum;
#pragma unroll
    for (int j = 0; j < 9; ++j) {
      const int i = tid * 9 + j;
      if (i < 513) off[i] = excl + local[j];
    }
  }
  __syncthreads();
  for (int b = tid; b < B; b += 1024) {
    const int p = atomicAdd(&off[lens[b]], 1);
    order[p] = b;
  }
}

// ---------------- Viterbi: 8 scan steps + path map (r12 exact) ----------
__device__ __forceinline__ void vit_map_block(const float (&pv)[8], int k, int len_eff,
                                              const float (&trc)[KK], float& a,
                                              int jj, int g, int r,
                                              uint32_t* __restrict__ s_map) {
  uint32_t bits = 0;
#pragma unroll
  for (int s = 0; s < 8; ++s) {
    const float av0 = swzf<BC0>(a), av1 = swzf<BC1>(a), av2 = swzf<BC2>(a),
                av3 = swzf<BC3>(a), av4 = swzf<BC4>(a);
    const float s0 = av0 + trc[0], s1 = av1 + trc[1], s2 = av2 + trc[2],
                s3 = av3 + trc[3], s4 = av4 + trc[4];
    const float bm = fmaxf(fmaxf(fmaxf(s0, s1), fmaxf(s2, s3)), s4);
    int bi = 4;                      // first-max tie-break == jnp.argmax
    bi = (s3 == bm) ? 3 : bi;
    bi = (s2 == bm) ? 2 : bi;
    bi = (s1 == bm) ? 1 : bi;
    bi = (s0 == bm) ? 0 : bi;
    const int t = k * 8 + s + 1;
    const bool act = (t < len_eff);
    a = act ? (bm + pv[s]) : a;
    const int bie = act ? bi : jj;   // identity backpointer when frozen
    bits |= (uint32_t)bie << (3 * s);
  }
  // gather the 5 tag-columns' bit words (independent bpermutes, one round)
  const uint32_t w0 = (uint32_t)__builtin_amdgcn_ds_bpermute(((g << 3) + 0) << 2, (int)bits);
  const uint32_t w1 = (uint32_t)__builtin_amdgcn_ds_bpermute(((g << 3) + 1) << 2, (int)bits);
  const uint32_t w2 = (uint32_t)__builtin_amdgcn_ds_bpermute(((g << 3) + 2) << 2, (int)bits);
  const uint32_t w3 = (uint32_t)__builtin_amdgcn_ds_bpermute(((g << 3) + 3) << 2, (int)bits);
  const uint32_t w4 = (uint32_t)__builtin_amdgcn_ds_bpermute(((g << 3) + 4) << 2, (int)bits);
  // in-register path map: exit tag jj -> 8 decoded tags (entry tag = dec & 7)
  int cur = jj;
  uint32_t dec = 0;
#pragma unroll
  for (int s = 7; s >= 0; --s) {
    const uint32_t w = sel5u(w0, w1, w2, w3, w4, cur);
    const int b3 = (int)((w >> (3 * s)) & 7u);
    dec |= (uint32_t)b3 << (3 * s);
    cur = b3;
  }
  if (r < 5) s_map[g * 321 + k * 5 + jj] = dec;
}

// ---------------- forward: 8 linear-space steps + fused score + renorm -----
__device__ __forceinline__ void fwd_blk(const float (&pv)[8], const int4 (&tp)[2],
                                        int k, int len, int len_eff,
                                        const float (&Wc)[KK], const float (&trcR)[KK],
                                        float& p, float& Cacc,
                                        float& pvcar, int& tagcar,
                                        float& usum, float& bsum, int r) {
#pragma unroll
  for (int s = 0; s < 8; ++s) {
    const float p0 = swzf<BC0>(p), p1 = swzf<BC1>(p), p2 = swzf<BC2>(p),
                p3 = swzf<BC3>(p), p4 = swzf<BC4>(p);
    const float u  = fmaf(p1, Wc[1], p0 * Wc[0]);
    const float v2 = fmaf(p3, Wc[3], p2 * Wc[2]);
    const float acc = fmaf(p4, Wc[4], u + v2);
    const float E = __expf(pv[s]);
    const int t = k * 8 + s + 1;
    const bool act = (t < len_eff);
    p = act ? (acc * E) : p;
  }
  // fused score over window t in [8k, 8k+7] (off the p chain)
#pragma unroll
  for (int s2 = 0; s2 < 8; ++s2) {
    const int t = k * 8 + s2;
    const int ct = telt(tp, s2);
    const int pt = (s2 == 0) ? tagcar : telt(tp, s2 - 1);
    const float potv = (s2 == 0) ? pvcar : pv[s2 - 1];
    const bool um = (t < len) && (ct == r);        // lanes 5..7 never match
    usum += um ? potv : 0.0f;
    bsum += (um && t >= 1) ? sel5f(trcR[0], trcR[1], trcR[2], trcR[3], trcR[4], pt) : 0.0f;
  }
  pvcar = pv[7];          // pot[8(k+1)][jj]
  tagcar = telt(tp, 7);   // tag[8k+7]
  // renorm once per block
  float m = p;
  m = fmaxf(m, swzf<X1>(m));
  m = fmaxf(m, swzf<X2>(m));
  m = fmaxf(m, swzf<X4>(m));           // lanes r>=5 hold p=0: never the max
  p *= (1.0f / m);
  Cacc += __logf(m);
}

// ---------------------------------------------------------------------------
// grid: 2*(B/8) blocks x 64 threads (1 wave). 8 sorted-adjacent batches/wave,
// 8 lanes/batch (5 compute tags). role via (blockIdx>>3)&1; blocks u and u+8
// share batches and XCD. No barriers anywhere.
// ---------------------------------------------------------------------------
__launch_bounds__(64)
__global__ void crf_kernel(const float* __restrict__ pot,
                           const float* __restrict__ trans,
                           const int* __restrict__ lens,
                           const int* __restrict__ tags,
                           const int* __restrict__ order,
                           float* __restrict__ out,
                           int B, int T) {
  __shared__ uint32_t s_map[8 * 321];   // [g][k][j], stride 321 breaks bank alias
  __shared__ uint32_t s_chosen[8 * 65];
  const int lane = threadIdx.x;
  const int g = lane >> 3, r = lane & 7;
  const int jj = (r < 5) ? r : 4;
  const unsigned u = blockIdx.x;
  const int role = (u >> 3) & 1;
  const int idx = (int)((u & 7u) | ((u >> 4) << 3));
  const int b = order[idx * 8 + g];     // sorted-by-length grouping
  const int len = lens[b];
  const int len_eff = (r < 5) ? len : 0;
  const float* __restrict__ prow = pot + (size_t)b * (T * KK);
  const float* __restrict__ colp = prow + jj;

  int ml = len;
  ml = max(ml, __shfl_xor(ml, 8));
  ml = max(ml, __shfl_xor(ml, 16));
  ml = max(ml, __shfl_xor(ml, 32));
  const int nblk = (ml + 7) >> 3;       // wave-uniform

  if (role == 0) {
    // ========================= Viterbi =========================
    float trc[KK];
#pragma unroll
    for (int i = 0; i < KK; ++i) trc[i] = trans[i * KK + jj];
    float a = (r < 5) ? prow[jj] : -3.0e38f;

    float pA[8], pB[8], pC[8];
    loadCol(pA, colp, 0);
    loadCol(pB, colp, min(1, nblk - 1));
    loadCol(pC, colp, min(2, nblk - 1));
    int blk = 0;
    while (true) {
      vit_map_block(pA, blk, len_eff, trc, a, jj, g, r, s_map);
      if (++blk == nblk) break;
      loadCol(pA, colp, min(blk + 2, nblk - 1));
      vit_map_block(pB, blk, len_eff, trc, a, jj, g, r, s_map);
      if (++blk == nblk) break;
      loadCol(pB, colp, min(blk + 2, nblk - 1));
      vit_map_block(pC, blk, len_eff, trc, a, jj, g, r, s_map);
      if (++blk == nblk) break;
      loadCol(pC, colp, min(blk + 2, nblk - 1));
    }
    // final argmax (first-max) over lanes r<5 of each group
    float bm = a;
    bm = fmaxf(bm, swzf<X1>(bm));
    bm = fmaxf(bm, swzf<X2>(bm));
    bm = fmaxf(bm, swzf<X4>(bm));
    int cand = (r < 5 && a == bm) ? r : 7;
    cand = min(cand, swzi<X1>(cand));
    cand = min(cand, swzi<X2>(cand));
    cand = min(cand, swzi<X4>(cand));
    const int last = cand;

    // backtrace via path maps
    if (r == 0) {
      int tag = last;
      for (int k2 = nblk - 1; k2 >= 0; --k2) {
        const uint32_t w = s_map[g * 321 + k2 * 5 + tag];
        s_chosen[g * 65 + k2] = w;
        tag = (int)(w & 7u);
      }
    }

    // coalesced decoded write
    float* __restrict__ orow = out + (size_t)b * T;
#pragma unroll
    for (int kk = 0; kk < 8; ++kk) {
      const int k2 = kk * 8 + r;
      const uint32_t w = s_chosen[g * 65 + k2];
      const int base = k2 * 8;
      float f[8];
#pragma unroll
      for (int pI = 0; pI < 8; ++pI)
        f[pI] = (base + pI < len) ? (float)((w >> (3 * pI)) & 7u) : 0.0f;
      *(float4*)(orow + base)     = make_float4(f[0], f[1], f[2], f[3]);
      *(float4*)(orow + base + 4) = make_float4(f[4], f[5], f[6], f[7]);
    }

  } else {
    // ==================== forward + fused score ====================
    float Wc[KK], trcR[KK];
#pragma unroll
    for (int i = 0; i < KK; ++i) {
      trcR[i] = trans[i * KK + jj];
      Wc[i] = __expf(trcR[i]);
    }
    const float pj0 = prow[jj];
    float p = (r < 5) ? __expf(pj0) : 0.0f;
    float Cacc = 0.0f;
    float usum = 0.0f, bsum = 0.0f;
    float pvcar = pj0;                   // pot[0][jj]
    int tagcar = 0;                      // unused at t=0 (binary starts t=1)
    const int* __restrict__ tg = tags + (size_t)b * T;

    float pA[8], pB[8], pC[8];
    int4 TA[2], TB[2], TC[2];
    loadCol(pA, colp, 0);                loadTag(TA, tg, 0);
    loadCol(pB, colp, min(1, nblk - 1)); loadTag(TB, tg, min(1, nblk - 1));
    loadCol(pC, colp, min(2, nblk - 1)); loadTag(TC, tg, min(2, nblk - 1));
    int blk = 0;
    while (true) {
      fwd_blk(pA, TA, blk, len, len_eff, Wc, trcR, p, Cacc, pvcar, tagcar, usum, bsum, r);
      if (++blk == nblk) break;
      loadCol(pA, colp, min(blk + 2, nblk - 1)); loadTag(TA, tg, min(blk + 2, nblk - 1));
      fwd_blk(pB, TB, blk, len, len_eff, Wc, trcR, p, Cacc, pvcar, tagcar, usum, bsum, r);
      if (++blk == nblk) break;
      loadCol(pB, colp, min(blk + 2, nblk - 1)); loadTag(TB, tg, min(blk + 2, nblk - 1));
      fwd_blk(pC, TC, blk, len, len_eff, Wc, trcR, p, Cacc, pvcar, tagcar, usum, bsum, r);
      if (++blk == nblk) break;
      loadCol(pC, colp, min(blk + 2, nblk - 1)); loadTag(TC, tg, min(blk + 2, nblk - 1));
    }
    // group totals
    float sc = usum + bsum;
    sc += swzf<X1>(sc);
    sc += swzf<X2>(sc);
    sc += swzf<X4>(sc);
    float ps = p;
    ps += swzf<X1>(ps);
    ps += swzf<X2>(ps);
    ps += swzf<X4>(ps);                  // lanes r>=5 contribute 0
    const float logZ = Cacc + __logf(ps);
    if (r == 0) out[(size_t)B * T + b] = sc - logZ;
  }
}

// ---------------------------------------------------------------------------
extern "C" void kernel_launch(void* const* d_in, const int* in_sizes, int n_in,
                              void* d_out, int out_size, void* d_ws, size_t ws_size,
                              hipStream_t stream) {
  const float* pot   = (const float*)d_in[0];
  const float* trans = (const float*)d_in[1];
  const int*   lens  = (const int*)d_in[2];
  const int*   tags  = (const int*)d_in[3];
  float* out = (float*)d_out;

  const int B = in_sizes[2];
  const int T = in_sizes[3] / B;   // 512

  int* order = (int*)d_ws;         // B ints

  sort_by_len<<<1, 1024, 0, stream>>>(lens, order, B);

  const int nblocks = 2 * (B / 8);  // 2048
  crf_kernel<<<nblocks, 64, 0, stream>>>(pot, trans, lens, tags, order, out, B, T);
}

// Round 14
// 90.878 us; speedup vs baseline: 1.0352x; 1.0352x over previous
//
#include <hip/hip_runtime.h>
#include <stdint.h>

#define KK 5
#define TT 512

// ---- cross-lane helpers (8-lane groups; 8 | 32 so groups never straddle the
// ds_swizzle 32-lane boundary) ----
template<int P> __device__ __forceinline__ float swzf(float v) {
  return __int_as_float(__builtin_amdgcn_ds_swizzle(__float_as_int(v), P));
}
template<int P> __device__ __forceinline__ int swzi(int v) {
  return __builtin_amdgcn_ds_swizzle(v, P);
}
// broadcast lane (group*8 + i): offset = (i<<5) | 0x18
#define BC0 0x018
#define BC1 0x038
#define BC2 0x058
#define BC3 0x078
#define BC4 0x098
// xor-butterfly within 8-lane group: offset = (m<<10) | 0x1F
#define X1 0x041F
#define X2 0x081F
#define X4 0x101F

__device__ __forceinline__ float sel5f(float v0,float v1,float v2,float v3,float v4,int ct){
  float u=v0; u=(ct==1)?v1:u; u=(ct==2)?v2:u; u=(ct==3)?v3:u; u=(ct==4)?v4:u; return u;
}
__device__ __forceinline__ uint32_t sel5u(uint32_t w0,uint32_t w1,uint32_t w2,uint32_t w3,uint32_t w4,int ct){
  uint32_t u=w0; u=(ct==1)?w1:u; u=(ct==2)?w2:u; u=(ct==3)?w3:u; u=(ct==4)?w4:u; return u;
}
__device__ __forceinline__ int telt(const int4 (&tp)[2], int s) {   // s compile-time
  const int4 v = (s < 4) ? tp[0] : tp[1];
  const int m = s & 3;
  return m == 0 ? v.x : (m == 1 ? v.y : (m == 2 ? v.z : v.w));
}

// load one 8-step column block: element t for t = 8k+1 .. 8k+8 (clamped)
__device__ __forceinline__ void loadCol(float (&d)[8], const float* __restrict__ colp, int k) {
  const int t0 = k * 8 + 1;
  if (k < TT / 8 - 1) {
#pragma unroll
    for (int s = 0; s < 8; ++s) d[s] = colp[(t0 + s) * KK];
  } else {
#pragma unroll
    for (int s = 0; s < 8; ++s) d[s] = colp[min(t0 + s, TT - 1) * KK];
  }
}
// aligned tag window [8k, 8k+7]
__device__ __forceinline__ void loadTag(int4 (&tp)[2], const int* __restrict__ tg, int k) {
  tp[0] = *(const int4*)(tg + 8 * k);
  tp[1] = *(const int4*)(tg + 8 * k + 4);
}

// ---------------------------------------------------------------------------
// Kernel 0: counting sort of batch indices by length, DESCENDING (LPT):
// longest waves dispatch first -> balanced per-CU work, short-wave backfill.
// ---------------------------------------------------------------------------
__global__ void sort_by_len(const int* __restrict__ lens, int* __restrict__ order, int B) {
  __shared__ int hist[513];
  __shared__ int off[513];
  const int tid = threadIdx.x;
  for (int i = tid; i < 513; i += 1024) hist[i] = 0;
  __syncthreads();
  for (int b = tid; b < B; b += 1024) atomicAdd(&hist[lens[b]], 1);
  __syncthreads();
  if (tid < 64) {
    int local[9];
    int sum = 0;
#pragma unroll
    for (int j = 0; j < 9; ++j) {
      const int i = tid * 9 + j;              // covers 0..575 >= 513
      const int v = (i < 513) ? hist[i] : 0;
      local[j] = sum;                          // lane-local exclusive
      sum += v;
    }
    int inc = sum;                             // wave inclusive scan
#pragma unroll
    for (int d = 1; d < 64; d <<= 1) {
      const int n = __shfl_up(inc, d);
      inc += (tid >= d) ? n : 0;
    }
    const int excl = inc - sum;
#pragma unroll
    for (int j = 0; j < 9; ++j) {
      const int i = tid * 9 + j;
      if (i < 513) off[i] = excl + local[j];
    }
  }
  __syncthreads();
  for (int b = tid; b < B; b += 1024) {
    const int p = atomicAdd(&off[lens[b]], 1);
    order[B - 1 - p] = b;                      // descending by length (LPT)
  }
}

// ---------------- Viterbi: 8 scan steps + path map (r12 exact) ----------
__device__ __forceinline__ void vit_map_block(const float (&pv)[8], int k, int len_eff,
                                              const float (&trc)[KK], float& a,
                                              int jj, int g, int r,
                                              uint32_t* __restrict__ s_map) {
  uint32_t bits = 0;
#pragma unroll
  for (int s = 0; s < 8; ++s) {
    const float av0 = swzf<BC0>(a), av1 = swzf<BC1>(a), av2 = swzf<BC2>(a),
                av3 = swzf<BC3>(a), av4 = swzf<BC4>(a);
    const float s0 = av0 + trc[0], s1 = av1 + trc[1], s2 = av2 + trc[2],
                s3 = av3 + trc[3], s4 = av4 + trc[4];
    const float bm = fmaxf(fmaxf(fmaxf(s0, s1), fmaxf(s2, s3)), s4);
    int bi = 4;                      // first-max tie-break == jnp.argmax
    bi = (s3 == bm) ? 3 : bi;
    bi = (s2 == bm) ? 2 : bi;
    bi = (s1 == bm) ? 1 : bi;
    bi = (s0 == bm) ? 0 : bi;
    const int t = k * 8 + s + 1;
    const bool act = (t < len_eff);
    a = act ? (bm + pv[s]) : a;
    const int bie = act ? bi : jj;   // identity backpointer when frozen
    bits |= (uint32_t)bie << (3 * s);
  }
  // gather the 5 tag-columns' bit words (independent bpermutes, one round)
  const uint32_t w0 = (uint32_t)__builtin_amdgcn_ds_bpermute(((g << 3) + 0) << 2, (int)bits);
  const uint32_t w1 = (uint32_t)__builtin_amdgcn_ds_bpermute(((g << 3) + 1) << 2, (int)bits);
  const uint32_t w2 = (uint32_t)__builtin_amdgcn_ds_bpermute(((g << 3) + 2) << 2, (int)bits);
  const uint32_t w3 = (uint32_t)__builtin_amdgcn_ds_bpermute(((g << 3) + 3) << 2, (int)bits);
  const uint32_t w4 = (uint32_t)__builtin_amdgcn_ds_bpermute(((g << 3) + 4) << 2, (int)bits);
  // in-register path map: exit tag jj -> 8 decoded tags (entry tag = dec & 7)
  int cur = jj;
  uint32_t dec = 0;
#pragma unroll
  for (int s = 7; s >= 0; --s) {
    const uint32_t w = sel5u(w0, w1, w2, w3, w4, cur);
    const int b3 = (int)((w >> (3 * s)) & 7u);
    dec |= (uint32_t)b3 << (3 * s);
    cur = b3;
  }
  if (r < 5) s_map[g * 321 + k * 5 + jj] = dec;
}

// ---------------- forward: 8 linear-space steps + fused score + renorm -----
__device__ __forceinline__ void fwd_blk(const float (&pv)[8], const int4 (&tp)[2],
                                        int k, int len, int len_eff,
                                        const float (&Wc)[KK], const float (&trcR)[KK],
                                        float& p, float& Cacc,
                                        float& pvcar, int& tagcar,
                                        float& usum, float& bsum, int r) {
#pragma unroll
  for (int s = 0; s < 8; ++s) {
    const float p0 = swzf<BC0>(p), p1 = swzf<BC1>(p), p2 = swzf<BC2>(p),
                p3 = swzf<BC3>(p), p4 = swzf<BC4>(p);
    const float u  = fmaf(p1, Wc[1], p0 * Wc[0]);
    const float v2 = fmaf(p3, Wc[3], p2 * Wc[2]);
    const float acc = fmaf(p4, Wc[4], u + v2);
    const float E = __expf(pv[s]);
    const int t = k * 8 + s + 1;
    const bool act = (t < len_eff);
    p = act ? (acc * E) : p;
  }
  // fused score over window t in [8k, 8k+7] (off the p chain)
#pragma unroll
  for (int s2 = 0; s2 < 8; ++s2) {
    const int t = k * 8 + s2;
    const int ct = telt(tp, s2);
    const int pt = (s2 == 0) ? tagcar : telt(tp, s2 - 1);
    const float potv = (s2 == 0) ? pvcar : pv[s2 - 1];
    const bool um = (t < len) && (ct == r);        // lanes 5..7 never match
    usum += um ? potv : 0.0f;
    bsum += (um && t >= 1) ? sel5f(trcR[0], trcR[1], trcR[2], trcR[3], trcR[4], pt) : 0.0f;
  }
  pvcar = pv[7];          // pot[8(k+1)][jj]
  tagcar = telt(tp, 7);   // tag[8k+7]
  // renorm once per block
  float m = p;
  m = fmaxf(m, swzf<X1>(m));
  m = fmaxf(m, swzf<X2>(m));
  m = fmaxf(m, swzf<X4>(m));           // lanes r>=5 hold p=0: never the max
  p *= (1.0f / m);
  Cacc += __logf(m);
}

// ---------------------------------------------------------------------------
// grid: 2*(B/8) blocks x 64 threads (1 wave). 8 sorted-adjacent batches/wave,
// 8 lanes/batch (5 compute tags). role via (blockIdx>>3)&1; blocks u and u+8
// share batches and XCD. No barriers anywhere.
// ---------------------------------------------------------------------------
__launch_bounds__(64)
__global__ void crf_kernel(const float* __restrict__ pot,
                           const float* __restrict__ trans,
                           const int* __restrict__ lens,
                           const int* __restrict__ tags,
                           const int* __restrict__ order,
                           float* __restrict__ out,
                           int B, int T) {
  __shared__ uint32_t s_map[8 * 321];   // [g][k][j], stride 321 breaks bank alias
  __shared__ uint32_t s_chosen[8 * 65];
  const int lane = threadIdx.x;
  const int g = lane >> 3, r = lane & 7;
  const int jj = (r < 5) ? r : 4;
  const unsigned u = blockIdx.x;
  const int role = (u >> 3) & 1;
  const int idx = (int)((u & 7u) | ((u >> 4) << 3));
  const int b = order[idx * 8 + g];     // sorted grouping, longest-first
  const int len = lens[b];
  const int len_eff = (r < 5) ? len : 0;
  const float* __restrict__ prow = pot + (size_t)b * (T * KK);
  const float* __restrict__ colp = prow + jj;

  int ml = len;
  ml = max(ml, __shfl_xor(ml, 8));
  ml = max(ml, __shfl_xor(ml, 16));
  ml = max(ml, __shfl_xor(ml, 32));
  const int nblk = (ml + 7) >> 3;       // wave-uniform

  if (role == 0) {
    // ========================= Viterbi =========================
    float trc[KK];
#pragma unroll
    for (int i = 0; i < KK; ++i) trc[i] = trans[i * KK + jj];
    float a = (r < 5) ? prow[jj] : -3.0e38f;

    float pA[8], pB[8], pC[8];
    loadCol(pA, colp, 0);
    loadCol(pB, colp, min(1, nblk - 1));
    loadCol(pC, colp, min(2, nblk - 1));
    int blk = 0;
    while (true) {
      vit_map_block(pA, blk, len_eff, trc, a, jj, g, r, s_map);
      if (++blk == nblk) break;
      loadCol(pA, colp, min(blk + 2, nblk - 1));
      vit_map_block(pB, blk, len_eff, trc, a, jj, g, r, s_map);
      if (++blk == nblk) break;
      loadCol(pB, colp, min(blk + 2, nblk - 1));
      vit_map_block(pC, blk, len_eff, trc, a, jj, g, r, s_map);
      if (++blk == nblk) break;
      loadCol(pC, colp, min(blk + 2, nblk - 1));
    }
    // final argmax (first-max) over lanes r<5 of each group
    float bm = a;
    bm = fmaxf(bm, swzf<X1>(bm));
    bm = fmaxf(bm, swzf<X2>(bm));
    bm = fmaxf(bm, swzf<X4>(bm));
    int cand = (r < 5 && a == bm) ? r : 7;
    cand = min(cand, swzi<X1>(cand));
    cand = min(cand, swzi<X2>(cand));
    cand = min(cand, swzi<X4>(cand));
    const int last = cand;

    // backtrace via path maps
    if (r == 0) {
      int tag = last;
      for (int k2 = nblk - 1; k2 >= 0; --k2) {
        const uint32_t w = s_map[g * 321 + k2 * 5 + tag];
        s_chosen[g * 65 + k2] = w;
        tag = (int)(w & 7u);
      }
    }

    // coalesced decoded write
    float* __restrict__ orow = out + (size_t)b * T;
#pragma unroll
    for (int kk = 0; kk < 8; ++kk) {
      const int k2 = kk * 8 + r;
      const uint32_t w = s_chosen[g * 65 + k2];
      const int base = k2 * 8;
      float f[8];
#pragma unroll
      for (int pI = 0; pI < 8; ++pI)
        f[pI] = (base + pI < len) ? (float)((w >> (3 * pI)) & 7u) : 0.0f;
      *(float4*)(orow + base)     = make_float4(f[0], f[1], f[2], f[3]);
      *(float4*)(orow + base + 4) = make_float4(f[4], f[5], f[6], f[7]);
    }

  } else {
    // ==================== forward + fused score ====================
    float Wc[KK], trcR[KK];
#pragma unroll
    for (int i = 0; i < KK; ++i) {
      trcR[i] = trans[i * KK + jj];
      Wc[i] = __expf(trcR[i]);
    }
    const float pj0 = prow[jj];
    float p = (r < 5) ? __expf(pj0) : 0.0f;
    float Cacc = 0.0f;
    float usum = 0.0f, bsum = 0.0f;
    float pvcar = pj0;                   // pot[0][jj]
    int tagcar = 0;                      // unused at t=0 (binary starts t=1)
    const int* __restrict__ tg = tags + (size_t)b * T;

    float pA[8], pB[8], pC[8];
    int4 TA[2], TB[2], TC[2];
    loadCol(pA, colp, 0);                loadTag(TA, tg, 0);
    loadCol(pB, colp, min(1, nblk - 1)); loadTag(TB, tg, min(1, nblk - 1));
    loadCol(pC, colp, min(2, nblk - 1)); loadTag(TC, tg, min(2, nblk - 1));
    int blk = 0;
    while (true) {
      fwd_blk(pA, TA, blk, len, len_eff, Wc, trcR, p, Cacc, pvcar, tagcar, usum, bsum, r);
      if (++blk == nblk) break;
      loadCol(pA, colp, min(blk + 2, nblk - 1)); loadTag(TA, tg, min(blk + 2, nblk - 1));
      fwd_blk(pB, TB, blk, len, len_eff, Wc, trcR, p, Cacc, pvcar, tagcar, usum, bsum, r);
      if (++blk == nblk) break;
      loadCol(pB, colp, min(blk + 2, nblk - 1)); loadTag(TB, tg, min(blk + 2, nblk - 1));
      fwd_blk(pC, TC, blk, len, len_eff, Wc, trcR, p, Cacc, pvcar, tagcar, usum, bsum, r);
      if (++blk == nblk) break;
      loadCol(pC, colp, min(blk + 2, nblk - 1)); loadTag(TC, tg, min(blk + 2, nblk - 1));
    }
    // group totals
    float sc = usum + bsum;
    sc += swzf<X1>(sc);
    sc += swzf<X2>(sc);
    sc += swzf<X4>(sc);
    float ps = p;
    ps += swzf<X1>(ps);
    ps += swzf<X2>(ps);
    ps += swzf<X4>(ps);                  // lanes r>=5 contribute 0
    const float logZ = Cacc + __logf(ps);
    if (r == 0) out[(size_t)B * T + b] = sc - logZ;
  }
}

// ---------------------------------------------------------------------------
extern "C" void kernel_launch(void* const* d_in, const int* in_sizes, int n_in,
                              void* d_out, int out_size, void* d_ws, size_t ws_size,
                              hipStream_t stream) {
  const float* pot   = (const float*)d_in[0];
  const float* trans = (const float*)d_in[1];
  const int*   lens  = (const int*)d_in[2];
  const int*   tags  = (const int*)d_in[3];
  float* out = (float*)d_out;

  const int B = in_sizes[2];
  const int T = in_sizes[3] / B;   // 512

  int* order = (int*)d_ws;         // B ints

  sort_by_len<<<1, 1024, 0, stream>>>(lens, order, B);

  const int nblocks = 2 * (B / 8);  // 2048
  crf_kernel<<<nblocks, 64, 0, stream>>>(pot, trans, lens, tags, order, out, B, T);
}